// Round 9
// baseline (115.185 us; speedup 1.0000x reference)
//
#include <hip/hip_runtime.h>

// Problem constants (fixed by reference)
#define BB 64
#define TT 512
#define MM 8
#define VMM 50
#define TBLK 128         // t per block
#define RSTRIDE 36       // u32 per LDS row: 32 data (64 bf16) + 4 pad
#define EPSV 1e-5f

// exp(score(h)-s0) lookup table, fp16x2-packed (value, delta)
#define TN   1024
#define HMAX 16.0f
#define HSTEP (HMAX / TN)
#define INVH  (TN / HMAX)

using short8  = __attribute__((ext_vector_type(8))) short;
using float4v = __attribute__((ext_vector_type(4))) float;

__device__ __forceinline__ float fast_rcp(float x) {
    return __builtin_amdgcn_rcpf(x);
}
__device__ __forceinline__ float fast_tanh(float x) {
    float e2 = __expf(2.0f * x);
    return fmaf(-2.0f, fast_rcp(e2 + 1.0f), 1.0f);
}
// round-to-nearest-even f32 -> bf16 pair packed into u32
__device__ __forceinline__ unsigned f2bf(float f) {
    unsigned u = __float_as_uint(f);
    return (u + 0x7FFFu + ((u >> 16) & 1u)) >> 16;
}
__device__ __forceinline__ unsigned pack2(float lo, float hi) {
    return f2bf(lo) | (f2bf(hi) << 16);
}
// f32 pair -> fp16x2 packed u32 (compiler-native _Float16, no fp16 header)
__device__ __forceinline__ unsigned packh2(float lo, float hi) {
    unsigned short a = __builtin_bit_cast(unsigned short, (_Float16)lo);
    unsigned short b = __builtin_bit_cast(unsigned short, (_Float16)hi);
    return (unsigned)a | ((unsigned)b << 16);
}
__device__ __forceinline__ float h2f_lo(unsigned p) {
    return (float)__builtin_bit_cast(_Float16, (unsigned short)(p & 0xFFFFu));
}
__device__ __forceinline__ float h2f_hi(unsigned p) {
    return (float)__builtin_bit_cast(_Float16, (unsigned short)(p >> 16));
}

// Single fused kernel: grid = B*M*(T/128) = 2048 blocks of 256 threads.
// amdgpu_waves_per_eu(4,4) pins the register allocator to exactly
// 4 waves/SIMD (<=128 VGPR) so it does NOT rematerialize down to 64.
__global__ __launch_bounds__(256)
__attribute__((amdgpu_waves_per_eu(4, 4)))
void intra_module_agg_kernel(const float* __restrict__ x,
                             const float* __restrict__ PA,
                             const float* __restrict__ conv_w,
                             const float* __restrict__ conv_b,
                             const float* __restrict__ bn_gamma,
                             const float* __restrict__ bn_beta,
                             const float* __restrict__ bn_mean,
                             const float* __restrict__ bn_var,
                             const float* __restrict__ w1,
                             const float* __restrict__ b1,
                             const float* __restrict__ w2,
                             const float* __restrict__ b2,
                             float* __restrict__ out)
{
    const int blk = blockIdx.x;
    const int tq  = blk & 3;          // T quarter
    const int m   = (blk >> 2) & 7;   // module
    const int b   = blk >> 5;         // batch
    const int j   = threadIdx.x;

    const int lane = j & 63, wv = j >> 6;
    const int q = lane >> 4, nl = lane & 15;

    __shared__ __align__(16) unsigned psu[64 * RSTRIDE];  // 9.2 KB PA^T bf16
    __shared__ __align__(16) unsigned gt[TN];             // 4.1 KB fp16x2 table

    // ---- per-module affine constants (wave-uniform -> scalar regs) ----
    const float scale = bn_gamma[m] * __frsqrt_rn(bn_var[m] + EPSV);
    const float Amul  = conv_w[m] * scale;
    const float Cadd  = (conv_b[m] - bn_mean[m]) * scale + bn_beta[m];

    // ---- issue x B-fragment loads FIRST (longest latency, HBM) ----
    // lane (nl,q) needs x[v = ks*32 + q*8 + jj][t], each instr = 4 fully-used
    // 64B lines. OOB v (>=50) clamped + zeroed.
    const int t0 = tq * TBLK;
    float xr[2][16];
#pragma unroll
    for (int t2 = 0; t2 < 2; ++t2) {
        const int t = t0 + (wv * 2 + t2) * 16 + nl;
        const float* xg = x + ((b * (MM * VMM) + m * VMM) * TT + t);
#pragma unroll
        for (int jj = 0; jj < 8; ++jj) {
            xr[t2][jj] = xg[(q * 8 + jj) * TT];            // v = 0..31, valid
        }
#pragma unroll
        for (int jj = 0; jj < 8; ++jj) {
            int v  = 32 + q * 8 + jj;                      // 32..63
            int vc = (v < VMM) ? v : 0;                    // safe address
            float tv = xg[vc * TT];
            xr[t2][8 + jj] = (v < VMM) ? tv : 0.0f;
        }
    }

    // ---- stage PA^T (w rows, v cols) into LDS, zero-padded to 64x64 ----
    {
        const float* pa = PA + m * (VMM * VMM);
        const int w  = j & 63;
        const int vb = (j >> 6) * 8;
#pragma unroll
        for (int i = 0; i < 8; ++i) {
            int vp = vb + i, v0 = 2 * vp, v1 = v0 + 1;
            float a = (w < VMM && v0 < VMM) ? pa[v0 * VMM + w] : 0.0f;
            float c = (w < VMM && v1 < VMM) ? pa[v1 * VMM + w] : 0.0f;
            psu[w * RSTRIDE + vp] = pack2(a, c);
        }
    }

    // ---- build table: gt[i] = fp16x2(g_i, g_{i+1}-g_i), g = exp(score-s0) --
    // Pure ALU: overlaps the x/PA load drain. softmax is shift-invariant;
    // s0 = smax-8 keeps exp() inside fp16 range.
    {
        float W1[8], B1[8], W2[8];
        float B2 = b2[m], sabs = 0.0f;
#pragma unroll
        for (int k = 0; k < 8; ++k) {
            W1[k] = w1[m * 8 + k];
            B1[k] = b1[m * 8 + k];
            W2[k] = w2[m * 8 + k];
            sabs += fabsf(W2[k]);
        }
        const float s0 = (B2 + sabs) - 8.0f;   // wave-uniform, bit-identical
        float gv[5];
#pragma unroll
        for (int k = 0; k < 5; ++k) {
            float h = (4 * j + k) * HSTEP;
            float s = B2 - s0;
#pragma unroll
            for (int i = 0; i < 8; ++i)
                s = fmaf(W2[i], fast_tanh(fmaf(h, W1[i], B1[i])), s);
            gv[k] = __expf(s);
        }
#pragma unroll
        for (int k = 0; k < 4; ++k)
            gt[4 * j + k] = packh2(gv[k], gv[k + 1] - gv[k]);
    }

    // ---- pack x to bf16 B-fragments (waits vmcnt while LDS writes drain) --
    short8 Bf[2][2];
#pragma unroll
    for (int t2 = 0; t2 < 2; ++t2) {
#pragma unroll
        for (int ks = 0; ks < 2; ++ks) {
            uint4 u;
            u.x = pack2(xr[t2][8 * ks + 0], xr[t2][8 * ks + 1]);
            u.y = pack2(xr[t2][8 * ks + 2], xr[t2][8 * ks + 3]);
            u.z = pack2(xr[t2][8 * ks + 4], xr[t2][8 * ks + 5]);
            u.w = pack2(xr[t2][8 * ks + 6], xr[t2][8 * ks + 7]);
            Bf[t2][ks] = __builtin_bit_cast(short8, u);
        }
    }

    __syncthreads();

    // ---- A fragments from LDS (r6-verified layout) ----
    short8 A[4][2];
#pragma unroll
    for (int wt = 0; wt < 4; ++wt)
#pragma unroll
        for (int ks = 0; ks < 2; ++ks)
            A[wt][ks] = *(const short8*)&psu[(wt * 16 + nl) * RSTRIDE + ks * 16 + q * 4];

    // ---- MFMA: C[w, t] = sum_v PA[v,w] * X[t,v] ----
    float4v C[2][4];
#pragma unroll
    for (int t2 = 0; t2 < 2; ++t2)
#pragma unroll
        for (int wt = 0; wt < 4; ++wt)
            C[t2][wt] = (float4v){0.f, 0.f, 0.f, 0.f};

#pragma unroll
    for (int t2 = 0; t2 < 2; ++t2) {
#pragma unroll
        for (int wt = 0; wt < 4; ++wt) {
            C[t2][wt] = __builtin_amdgcn_mfma_f32_16x16x32_bf16(A[wt][0], Bf[t2][0], C[t2][wt], 0, 0, 0);
            C[t2][wt] = __builtin_amdgcn_mfma_f32_16x16x32_bf16(A[wt][1], Bf[t2][1], C[t2][wt], 0, 0, 0);
        }
    }

    // ---- epilogue: table softmax over w (rows in-thread, quads via shfl) --
    const int obase = (b * MM + m) * TT + t0;
#pragma unroll
    for (int t2 = 0; t2 < 2; ++t2) {
        float se = 0.0f, sh = 0.0f;
#pragma unroll
        for (int wt = 0; wt < 4; ++wt) {
#pragma unroll
            for (int r = 0; r < 4; ++r) {
                const int w = wt * 16 + q * 4 + r;
                float h = fmaxf(fmaf(C[t2][wt][r], Amul, Cadd), 0.0f);
                float u = fminf(h, HMAX - 0.0005f) * INVH;
                int   i = (int)u;
                float fr = u - (float)i;
                unsigned p = gt[i];
                float e = (w < VMM) ? fmaf(fr, h2f_hi(p), h2f_lo(p)) : 0.0f;
                se += e;
                sh = fmaf(h, e, sh);
            }
        }
        se += __shfl_xor(se, 16, 64);
        se += __shfl_xor(se, 32, 64);
        sh += __shfl_xor(sh, 16, 64);
        sh += __shfl_xor(sh, 32, 64);
        if (q == 0)
            out[obase + (wv * 2 + t2) * 16 + nl] = sh * fast_rcp(se);
    }
}

extern "C" void kernel_launch(void* const* d_in, const int* in_sizes, int n_in,
                              void* d_out, int out_size, void* d_ws, size_t ws_size,
                              hipStream_t stream) {
    const float* x        = (const float*)d_in[0];
    const float* PA       = (const float*)d_in[1];
    const float* conv_w   = (const float*)d_in[2];
    const float* conv_b   = (const float*)d_in[3];
    const float* bn_gamma = (const float*)d_in[4];
    const float* bn_beta  = (const float*)d_in[5];
    const float* bn_mean  = (const float*)d_in[6];
    const float* bn_var   = (const float*)d_in[7];
    const float* w1       = (const float*)d_in[8];
    const float* b1       = (const float*)d_in[9];
    const float* w2       = (const float*)d_in[10];
    const float* b2       = (const float*)d_in[11];
    float* out = (float*)d_out;

    intra_module_agg_kernel<<<dim3(BB * MM * (TT / TBLK)), dim3(256), 0, stream>>>(
        x, PA, conv_w, conv_b, bn_gamma, bn_beta, bn_mean, bn_var,
        w1, b1, w2, b2, out);
}

// Round 10
// 110.342 us; speedup vs baseline: 1.0439x; 1.0439x over previous
//
#include <hip/hip_runtime.h>

// Problem constants (fixed by reference)
#define BB 64
#define TT 512
#define MM 8
#define VMM 50
#define TBLK 128         // t per tile; 2 tiles per block
#define EPSV 1e-5f

// exp(score(h)-s0) lookup table, fp16x2-packed (value, delta)
#define TN   1024
#define HMAX 16.0f
#define HSTEP (HMAX / TN)
#define INVH  (TN / HMAX)

// d_ws layout (u32 units):
//   [0, 8*TN)          : 8 per-module fp16x2 tables
//   [8*TN, +8*2048)    : 8 per-module PA^T in MFMA A-fragment order
#define WS_GT(m)   ((m) * TN)
#define WS_PAF(m)  (MM * TN + (m) * (8 * 64 * 4))
#define WS_NEED    ((MM * TN + MM * 8 * 64 * 4) * 4)   // 98304 bytes

using short8  = __attribute__((ext_vector_type(8))) short;
using float4v = __attribute__((ext_vector_type(4))) float;

__device__ __forceinline__ float fast_rcp(float x) {
    return __builtin_amdgcn_rcpf(x);
}
__device__ __forceinline__ float fast_tanh(float x) {
    float e2 = __expf(2.0f * x);
    return fmaf(-2.0f, fast_rcp(e2 + 1.0f), 1.0f);
}
__device__ __forceinline__ unsigned f2bf(float f) {
    unsigned u = __float_as_uint(f);
    return (u + 0x7FFFu + ((u >> 16) & 1u)) >> 16;
}
__device__ __forceinline__ unsigned pack2(float lo, float hi) {
    return f2bf(lo) | (f2bf(hi) << 16);
}
__device__ __forceinline__ unsigned packh2(float lo, float hi) {
    unsigned short a = __builtin_bit_cast(unsigned short, (_Float16)lo);
    unsigned short b = __builtin_bit_cast(unsigned short, (_Float16)hi);
    return (unsigned)a | ((unsigned)b << 16);
}
__device__ __forceinline__ float h2f_lo(unsigned p) {
    return (float)__builtin_bit_cast(_Float16, (unsigned short)(p & 0xFFFFu));
}
__device__ __forceinline__ float h2f_hi(unsigned p) {
    return (float)__builtin_bit_cast(_Float16, (unsigned short)(p >> 16));
}

// ---------------- prep kernel: 8 blocks, one per module (r8-verified) ----
__global__ __launch_bounds__(256, 4)
void prep_kernel(const float* __restrict__ PA,
                 const float* __restrict__ w1,
                 const float* __restrict__ b1,
                 const float* __restrict__ w2,
                 const float* __restrict__ b2,
                 unsigned* __restrict__ ws)
{
    const int m = blockIdx.x;
    const int j = threadIdx.x;

    {
        float W1[8], B1[8], W2[8];
        float B2 = b2[m], sabs = 0.0f;
#pragma unroll
        for (int k = 0; k < 8; ++k) {
            W1[k] = w1[m * 8 + k];
            B1[k] = b1[m * 8 + k];
            W2[k] = w2[m * 8 + k];
            sabs += fabsf(W2[k]);
        }
        const float s0 = (B2 + sabs) - 8.0f;   // uniform shift; exp in fp16 range
        float gv[5];
#pragma unroll
        for (int k = 0; k < 5; ++k) {
            float h = (4 * j + k) * HSTEP;
            float s = B2 - s0;
#pragma unroll
            for (int i = 0; i < 8; ++i)
                s = fmaf(W2[i], fast_tanh(fmaf(h, W1[i], B1[i])), s);
            gv[k] = __expf(s);
        }
#pragma unroll
        for (int k = 0; k < 4; ++k)
            ws[WS_GT(m) + 4 * j + k] = packh2(gv[k], gv[k + 1] - gv[k]);
    }

    // PA^T packed straight into A-fragment order:
    // fragment A[wt][ks] for lane: w = wt*16 + (lane&15),
    // u32 cols vp = ks*16 + (lane>>4)*4 + 0..3 (bf16 v = 2vp, 2vp+1).
    {
        const float* pa = PA + m * (VMM * VMM);
        uint4* dst = (uint4*)(ws + WS_PAF(m));
#pragma unroll
        for (int p = 0; p < 2; ++p) {
            int id   = j + p * 256;        // 0..511
            int wt   = id >> 7;
            int ks   = (id >> 6) & 1;
            int lane = id & 63;
            int w    = wt * 16 + (lane & 15);
            int vp0  = ks * 16 + (lane >> 4) * 4;
            unsigned u[4];
#pragma unroll
            for (int k = 0; k < 4; ++k) {
                int vp = vp0 + k, v0 = 2 * vp, v1 = v0 + 1;
                float a = (w < VMM && v0 < VMM) ? pa[v0 * VMM + w] : 0.0f;
                float c = (w < VMM && v1 < VMM) ? pa[v1 * VMM + w] : 0.0f;
                u[k] = pack2(a, c);
            }
            dst[(wt * 2 + ks) * 64 + lane] = make_uint4(u[0], u[1], u[2], u[3]);
        }
    }
}

// ---------------- main kernel: grid = B*M*(T/256) = 1024 ----------------
// Two 128-t tiles per block, software-pipelined: both tiles' x loads are
// issued before any compute; a RAW s_barrier (lgkmcnt-only wait) publishes
// gt without draining tile-B's in-flight global loads (the compiler's
// __syncthreads would force vmcnt(0)).
__global__ __launch_bounds__(256)
void intra_module_agg_kernel(const float* __restrict__ x,
                             const float* __restrict__ conv_w,
                             const float* __restrict__ conv_b,
                             const float* __restrict__ bn_gamma,
                             const float* __restrict__ bn_beta,
                             const float* __restrict__ bn_mean,
                             const float* __restrict__ bn_var,
                             const unsigned* __restrict__ ws,
                             float* __restrict__ out)
{
    const int blk = blockIdx.x;
    const int th  = blk & 1;          // T half
    const int m   = (blk >> 1) & 7;   // module
    const int b   = blk >> 4;         // batch
    const int j   = threadIdx.x;

    const int lane = j & 63, wv = j >> 6;
    const int q = lane >> 4, nl = lane & 15;

    __shared__ __align__(16) unsigned gt[TN];   // 4.1 KB only

    const float scale = bn_gamma[m] * __frsqrt_rn(bn_var[m] + EPSV);
    const float Amul  = conv_w[m] * scale;
    const float Cadd  = (conv_b[m] - bn_mean[m]) * scale + bn_beta[m];

    const int t0 = th * 256;
    const float* xgb = x + ((b * (MM * VMM) + m * VMM) * TT);

    // ---- 1) issue tile-A x loads (HBM, longest latency) ----
    float xa[2][16];
#pragma unroll
    for (int t2 = 0; t2 < 2; ++t2) {
        const int t = t0 + (wv * 2 + t2) * 16 + nl;
        const float* xg = xgb + t;
#pragma unroll
        for (int jj = 0; jj < 8; ++jj)
            xa[t2][jj] = xg[(q * 8 + jj) * TT];
#pragma unroll
        for (int jj = 0; jj < 8; ++jj) {
            int v  = 32 + q * 8 + jj;
            int vc = (v < VMM) ? v : 0;
            float tv = xg[vc * TT];
            xa[t2][8 + jj] = (v < VMM) ? tv : 0.0f;
        }
    }

    // ---- 2) gt + A-fragments (L2-hot) ----
    uint4 g = ((const uint4*)(ws + WS_GT(m)))[j];
    const uint4* paf = (const uint4*)(ws + WS_PAF(m));
    uint4 Araw[4][2];
#pragma unroll
    for (int wt = 0; wt < 4; ++wt)
#pragma unroll
        for (int ks = 0; ks < 2; ++ks)
            Araw[wt][ks] = paf[(wt * 2 + ks) * 64 + lane];

    // ---- 3) issue tile-B x loads; pin so they cannot be sunk ----
    float xb_[2][16];
#pragma unroll
    for (int t2 = 0; t2 < 2; ++t2) {
        const int t = t0 + TBLK + (wv * 2 + t2) * 16 + nl;
        const float* xg = xgb + t;
#pragma unroll
        for (int jj = 0; jj < 8; ++jj)
            xb_[t2][jj] = xg[(q * 8 + jj) * TT];
#pragma unroll
        for (int jj = 0; jj < 8; ++jj) {
            int v  = 32 + q * 8 + jj;
            int vc = (v < VMM) ? v : 0;
            float tv = xg[vc * TT];
            xb_[t2][8 + jj] = (v < VMM) ? tv : 0.0f;
        }
    }
#pragma unroll
    for (int t2 = 0; t2 < 2; ++t2)
#pragma unroll
        for (int i = 0; i < 16; ++i) asm volatile("" : "+v"(xb_[t2][i]));

    // ---- 4) publish gt (needs only g; FIFO wait leaves tile-B in flight) --
    *(uint4*)&gt[4 * j] = g;

    // ---- 5) pack tile-A fragments ----
    short8 BfA[2][2];
#pragma unroll
    for (int t2 = 0; t2 < 2; ++t2)
#pragma unroll
        for (int ks = 0; ks < 2; ++ks) {
            uint4 u;
            u.x = pack2(xa[t2][8 * ks + 0], xa[t2][8 * ks + 1]);
            u.y = pack2(xa[t2][8 * ks + 2], xa[t2][8 * ks + 3]);
            u.z = pack2(xa[t2][8 * ks + 4], xa[t2][8 * ks + 5]);
            u.w = pack2(xa[t2][8 * ks + 6], xa[t2][8 * ks + 7]);
            BfA[t2][ks] = __builtin_bit_cast(short8, u);
        }

    // ---- 6) raw barrier: wait own LDS write only, do NOT drain vmcnt ----
    asm volatile("s_waitcnt lgkmcnt(0)\n\ts_barrier" ::: "memory");

    // ---- 7) MFMA + epilogue, tile A ----
    const int obase = (b * MM + m) * TT + t0;
#pragma unroll
    for (int half = 0; half < 2; ++half) {
        short8 Bf[2][2];
        if (half == 0) {
#pragma unroll
            for (int t2 = 0; t2 < 2; ++t2)
#pragma unroll
                for (int ks = 0; ks < 2; ++ks) Bf[t2][ks] = BfA[t2][ks];
        } else {
#pragma unroll
            for (int t2 = 0; t2 < 2; ++t2)
#pragma unroll
                for (int ks = 0; ks < 2; ++ks) {
                    uint4 u;
                    u.x = pack2(xb_[t2][8 * ks + 0], xb_[t2][8 * ks + 1]);
                    u.y = pack2(xb_[t2][8 * ks + 2], xb_[t2][8 * ks + 3]);
                    u.z = pack2(xb_[t2][8 * ks + 4], xb_[t2][8 * ks + 5]);
                    u.w = pack2(xb_[t2][8 * ks + 6], xb_[t2][8 * ks + 7]);
                    Bf[t2][ks] = __builtin_bit_cast(short8, u);
                }
        }

        float4v C[2][4];
#pragma unroll
        for (int t2 = 0; t2 < 2; ++t2)
#pragma unroll
            for (int wt = 0; wt < 4; ++wt)
                C[t2][wt] = (float4v){0.f, 0.f, 0.f, 0.f};

#pragma unroll
        for (int t2 = 0; t2 < 2; ++t2)
#pragma unroll
            for (int wt = 0; wt < 4; ++wt) {
                C[t2][wt] = __builtin_amdgcn_mfma_f32_16x16x32_bf16(
                    __builtin_bit_cast(short8, Araw[wt][0]), Bf[t2][0], C[t2][wt], 0, 0, 0);
                C[t2][wt] = __builtin_amdgcn_mfma_f32_16x16x32_bf16(
                    __builtin_bit_cast(short8, Araw[wt][1]), Bf[t2][1], C[t2][wt], 0, 0, 0);
            }

        const int ob = obase + half * TBLK;
#pragma unroll
        for (int t2 = 0; t2 < 2; ++t2) {
            float se = 0.0f, sh = 0.0f;
#pragma unroll
            for (int wt = 0; wt < 4; ++wt) {
#pragma unroll
                for (int r = 0; r < 4; ++r) {
                    const int w = wt * 16 + q * 4 + r;
                    float h = fmaxf(fmaf(C[t2][wt][r], Amul, Cadd), 0.0f);
                    float u = fminf(h, HMAX - 0.0005f) * INVH;
                    int   i = (int)u;
                    float fr = u - (float)i;
                    unsigned p = gt[i];
                    float e = (w < VMM) ? fmaf(fr, h2f_hi(p), h2f_lo(p)) : 0.0f;
                    se += e;
                    sh = fmaf(h, e, sh);
                }
            }
            se += __shfl_xor(se, 16, 64);
            se += __shfl_xor(se, 32, 64);
            sh += __shfl_xor(sh, 16, 64);
            sh += __shfl_xor(sh, 32, 64);
            if (q == 0)
                out[ob + (wv * 2 + t2) * 16 + nl] = sh * fast_rcp(se);
        }
    }
}

// ---------------- fallback monolithic kernel (round-6, verified) --------
#define RSTRIDE 36
__global__ __launch_bounds__(256, 4)
void mono_kernel(const float* __restrict__ x,
                 const float* __restrict__ PA,
                 const float* __restrict__ conv_w,
                 const float* __restrict__ conv_b,
                 const float* __restrict__ bn_gamma,
                 const float* __restrict__ bn_beta,
                 const float* __restrict__ bn_mean,
                 const float* __restrict__ bn_var,
                 const float* __restrict__ w1,
                 const float* __restrict__ b1,
                 const float* __restrict__ w2,
                 const float* __restrict__ b2,
                 float* __restrict__ out)
{
    const int blk = blockIdx.x;
    const int tq  = blk & 3;
    const int m   = (blk >> 2) & 7;
    const int b   = blk >> 5;
    const int j   = threadIdx.x;

    __shared__ __align__(16) unsigned xsu[TBLK * RSTRIDE];
    __shared__ __align__(16) unsigned psu[64 * RSTRIDE];
    __shared__ __align__(16) unsigned gt[TN];

    const float scale = bn_gamma[m] * __frsqrt_rn(bn_var[m] + EPSV);
    const float Amul  = conv_w[m] * scale;
    const float Cadd  = (conv_b[m] - bn_mean[m]) * scale + bn_beta[m];

    {
        const int t  = j >> 1;
        const int hf = j & 1;
        const float* xb = x + ((b * (MM * VMM) + m * VMM) * TT + tq * TBLK + t);
        unsigned* row = &xsu[t * RSTRIDE];
        const int vp0 = hf * 13;
#pragma unroll
        for (int i = 0; i < 13; ++i) {
            int vp = vp0 + i;
            float a = 0.0f, c = 0.0f;
            if (vp < 25) { a = xb[(2 * vp) * TT]; c = xb[(2 * vp + 1) * TT]; }
            row[vp] = pack2(a, c);
        }
        if (hf) {
#pragma unroll
            for (int vp = 26; vp < 32; ++vp) row[vp] = 0u;
        }
    }
    {
        const float* pa = PA + m * (VMM * VMM);
        const int w  = j & 63;
        const int vb = (j >> 6) * 8;
#pragma unroll
        for (int i = 0; i < 8; ++i) {
            int vp = vb + i, v0 = 2 * vp, v1 = v0 + 1;
            float a = (w < VMM && v0 < VMM) ? pa[v0 * VMM + w] : 0.0f;
            float c = (w < VMM && v1 < VMM) ? pa[v1 * VMM + w] : 0.0f;
            psu[w * RSTRIDE + vp] = pack2(a, c);
        }
    }
    {
        float W1[8], B1[8], W2[8];
        float B2 = b2[m], sabs = 0.0f;
#pragma unroll
        for (int k = 0; k < 8; ++k) {
            W1[k] = w1[m * 8 + k];
            B1[k] = b1[m * 8 + k];
            W2[k] = w2[m * 8 + k];
            sabs += fabsf(W2[k]);
        }
        const float s0 = (B2 + sabs) - 8.0f;
        float gv[5];
#pragma unroll
        for (int k = 0; k < 5; ++k) {
            float h = (4 * j + k) * HSTEP;
            float s = B2 - s0;
#pragma unroll
            for (int i = 0; i < 8; ++i)
                s = fmaf(W2[i], fast_tanh(fmaf(h, W1[i], B1[i])), s);
            gv[k] = __expf(s);
        }
#pragma unroll
        for (int k = 0; k < 4; ++k)
            gt[4 * j + k] = packh2(gv[k], gv[k + 1] - gv[k]);
    }

    __syncthreads();

    const int lane = j & 63, wv = j >> 6;
    const int q = lane >> 4, nl = lane & 15;

    short8 A[4][2];
#pragma unroll
    for (int wt = 0; wt < 4; ++wt)
#pragma unroll
        for (int ks = 0; ks < 2; ++ks)
            A[wt][ks] = *(const short8*)&psu[(wt * 16 + nl) * RSTRIDE + ks * 16 + q * 4];

    float4v C[2][4];
#pragma unroll
    for (int t2 = 0; t2 < 2; ++t2)
#pragma unroll
        for (int wt = 0; wt < 4; ++wt)
            C[t2][wt] = (float4v){0.f, 0.f, 0.f, 0.f};

#pragma unroll
    for (int t2 = 0; t2 < 2; ++t2) {
        const int trow = (wv * 2 + t2) * 16 + nl;
        short8 Bv0 = *(const short8*)&xsu[trow * RSTRIDE + 0 * 16 + q * 4];
        short8 Bv1 = *(const short8*)&xsu[trow * RSTRIDE + 1 * 16 + q * 4];
#pragma unroll
        for (int wt = 0; wt < 4; ++wt) {
            C[t2][wt] = __builtin_amdgcn_mfma_f32_16x16x32_bf16(A[wt][0], Bv0, C[t2][wt], 0, 0, 0);
            C[t2][wt] = __builtin_amdgcn_mfma_f32_16x16x32_bf16(A[wt][1], Bv1, C[t2][wt], 0, 0, 0);
        }
    }

    const int obase = (b * MM + m) * TT + tq * TBLK;
#pragma unroll
    for (int t2 = 0; t2 < 2; ++t2) {
        float se = 0.0f, sh = 0.0f;
#pragma unroll
        for (int wt = 0; wt < 4; ++wt) {
#pragma unroll
            for (int r = 0; r < 4; ++r) {
                const int w = wt * 16 + q * 4 + r;
                float h = fmaxf(fmaf(C[t2][wt][r], Amul, Cadd), 0.0f);
                float u = fminf(h, HMAX - 0.0005f) * INVH;
                int   i = (int)u;
                float fr = u - (float)i;
                unsigned p = gt[i];
                float e = (w < VMM) ? fmaf(fr, h2f_hi(p), h2f_lo(p)) : 0.0f;
                se += e;
                sh = fmaf(h, e, sh);
            }
        }
        se += __shfl_xor(se, 16, 64);
        se += __shfl_xor(se, 32, 64);
        sh += __shfl_xor(sh, 16, 64);
        sh += __shfl_xor(sh, 32, 64);
        if (q == 0)
            out[obase + (wv * 2 + t2) * 16 + nl] = sh * fast_rcp(se);
    }
}

extern "C" void kernel_launch(void* const* d_in, const int* in_sizes, int n_in,
                              void* d_out, int out_size, void* d_ws, size_t ws_size,
                              hipStream_t stream) {
    const float* x        = (const float*)d_in[0];
    const float* PA       = (const float*)d_in[1];
    const float* conv_w   = (const float*)d_in[2];
    const float* conv_b   = (const float*)d_in[3];
    const float* bn_gamma = (const float*)d_in[4];
    const float* bn_beta  = (const float*)d_in[5];
    const float* bn_mean  = (const float*)d_in[6];
    const float* bn_var   = (const float*)d_in[7];
    const float* w1       = (const float*)d_in[8];
    const float* b1       = (const float*)d_in[9];
    const float* w2       = (const float*)d_in[10];
    const float* b2       = (const float*)d_in[11];
    float* out = (float*)d_out;

    if (ws_size >= (size_t)WS_NEED) {
        unsigned* ws = (unsigned*)d_ws;
        prep_kernel<<<dim3(MM), dim3(256), 0, stream>>>(PA, w1, b1, w2, b2, ws);
        intra_module_agg_kernel<<<dim3(BB * MM * (TT / 256)), dim3(256), 0, stream>>>(
            x, conv_w, conv_b, bn_gamma, bn_beta, bn_mean, bn_var, ws, out);
    } else {
        mono_kernel<<<dim3(BB * MM * (TT / TBLK)), dim3(256), 0, stream>>>(
            x, PA, conv_w, conv_b, bn_gamma, bn_beta, bn_mean, bn_var,
            w1, b1, w2, b2, out);
    }
}

// Round 11
// 110.149 us; speedup vs baseline: 1.0457x; 1.0018x over previous
//
#include <hip/hip_runtime.h>

// Problem constants (fixed by reference)
#define BB 64
#define TT 512
#define MM 8
#define VMM 50
#define RSTRIDE 36       // u32 per LDS row: 32 data (64 bf16) + 4 pad
#define EPSV 1e-5f

// exp(score(h)-s0) lookup table, fp16x2-packed (value, delta)
#define TN   1024
#define HMAX 16.0f
#define HSTEP (HMAX / TN)
#define INVH  (TN / HMAX)

using short8  = __attribute__((ext_vector_type(8))) short;
using float4v = __attribute__((ext_vector_type(4))) float;

__device__ __forceinline__ float fast_rcp(float x) {
    return __builtin_amdgcn_rcpf(x);
}
__device__ __forceinline__ float fast_tanh(float x) {
    float e2 = __expf(2.0f * x);
    return fmaf(-2.0f, fast_rcp(e2 + 1.0f), 1.0f);
}
__device__ __forceinline__ unsigned f2bf(float f) {
    unsigned u = __float_as_uint(f);
    return (u + 0x7FFFu + ((u >> 16) & 1u)) >> 16;
}
__device__ __forceinline__ unsigned pack2(float lo, float hi) {
    return f2bf(lo) | (f2bf(hi) << 16);
}
__device__ __forceinline__ unsigned packh2(float lo, float hi) {
    unsigned short a = __builtin_bit_cast(unsigned short, (_Float16)lo);
    unsigned short b = __builtin_bit_cast(unsigned short, (_Float16)hi);
    return (unsigned)a | ((unsigned)b << 16);
}
__device__ __forceinline__ float h2f_lo(unsigned p) {
    return (float)__builtin_bit_cast(_Float16, (unsigned short)(p & 0xFFFFu));
}
__device__ __forceinline__ float h2f_hi(unsigned p) {
    return (float)__builtin_bit_cast(_Float16, (unsigned short)(p >> 16));
}

// Load one 128-t tile's B-operand x values for this thread.
// lane (nl,q) covers v = {q*8+jj} and {32+q*8+jj}; one instr = 4 fully-used
// 64B lines. OOB v (>=50) clamped + zeroed.
__device__ __forceinline__ void load_tile(const float* __restrict__ xgb,
                                          int t0, int wv, int nl, int q,
                                          float xr[2][16])
{
#pragma unroll
    for (int t2 = 0; t2 < 2; ++t2) {
        const float* xg = xgb + t0 + (wv * 2 + t2) * 16 + nl;
#pragma unroll
        for (int jj = 0; jj < 8; ++jj)
            xr[t2][jj] = xg[(q * 8 + jj) * TT];            // v = 0..31, valid
#pragma unroll
        for (int jj = 0; jj < 8; ++jj) {
            int v  = 32 + q * 8 + jj;                      // 32..63
            int vc = (v < VMM) ? v : 0;                    // safe address
            float tv = xg[vc * TT];
            xr[t2][8 + jj] = (v < VMM) ? tv : 0.0f;
        }
    }
}

__device__ __forceinline__ void pack_tile(const float xr[2][16], short8 Bf[2][2])
{
#pragma unroll
    for (int t2 = 0; t2 < 2; ++t2)
#pragma unroll
        for (int ks = 0; ks < 2; ++ks) {
            uint4 u;
            u.x = pack2(xr[t2][8 * ks + 0], xr[t2][8 * ks + 1]);
            u.y = pack2(xr[t2][8 * ks + 2], xr[t2][8 * ks + 3]);
            u.z = pack2(xr[t2][8 * ks + 4], xr[t2][8 * ks + 5]);
            u.w = pack2(xr[t2][8 * ks + 6], xr[t2][8 * ks + 7]);
            Bf[t2][ks] = __builtin_bit_cast(short8, u);
        }
}

// Single fused kernel: grid = B*M = 512 blocks of 256 threads.
// Each block owns one (b,m) and all T=512 (4 tiles of 128), so the
// per-block fixed work (PA stage, table build, barrier, A-frags) is
// amortized 4x. Depth-2 software pipeline on the x tiles; a raw
// lgkmcnt-only s_barrier publishes LDS without draining in-flight
// global loads. waves_per_eu(2) matches the grid-limited occupancy
// (2 blocks/CU) and gives the allocator the full register budget.
__global__ __launch_bounds__(256)
__attribute__((amdgpu_waves_per_eu(2)))
void intra_module_agg_kernel(const float* __restrict__ x,
                             const float* __restrict__ PA,
                             const float* __restrict__ conv_w,
                             const float* __restrict__ conv_b,
                             const float* __restrict__ bn_gamma,
                             const float* __restrict__ bn_beta,
                             const float* __restrict__ bn_mean,
                             const float* __restrict__ bn_var,
                             const float* __restrict__ w1,
                             const float* __restrict__ b1,
                             const float* __restrict__ w2,
                             const float* __restrict__ b2,
                             float* __restrict__ out)
{
    const int blk = blockIdx.x;
    const int m   = blk & 7;
    const int b   = blk >> 3;
    const int j   = threadIdx.x;

    const int lane = j & 63, wv = j >> 6;
    const int q = lane >> 4, nl = lane & 15;

    __shared__ __align__(16) unsigned psu[64 * RSTRIDE];  // 9.2 KB PA^T bf16
    __shared__ __align__(16) unsigned gt[TN];             // 4.1 KB fp16x2 table

    const float scale = bn_gamma[m] * __frsqrt_rn(bn_var[m] + EPSV);
    const float Amul  = conv_w[m] * scale;
    const float Cadd  = (conv_b[m] - bn_mean[m]) * scale + bn_beta[m];

    const float* xgb = x + ((b * (MM * VMM) + m * VMM) * TT);

    // ---- 1) issue tiles 0 and 1 x loads (HBM, longest latency) ----
    float xr[2][2][16];
    load_tile(xgb, 0 * 128, wv, nl, q, xr[0]);
    load_tile(xgb, 1 * 128, wv, nl, q, xr[1]);

    // ---- 2) stage PA^T into LDS (coalesced loads, zero-padded 64x64) ----
    {
        const float* pa = PA + m * (VMM * VMM);
        const int w  = j & 63;
        const int vb = (j >> 6) * 8;
#pragma unroll
        for (int i = 0; i < 8; ++i) {
            int vp = vb + i, v0 = 2 * vp, v1 = v0 + 1;
            float a = (w < VMM && v0 < VMM) ? pa[v0 * VMM + w] : 0.0f;
            float c = (w < VMM && v1 < VMM) ? pa[v1 * VMM + w] : 0.0f;
            psu[w * RSTRIDE + vp] = pack2(a, c);
        }
    }

    // ---- 3) build gt table (pure ALU, overlaps the load drain) ----
    {
        float W1[8], B1[8], W2[8];
        float B2 = b2[m], sabs = 0.0f;
#pragma unroll
        for (int k = 0; k < 8; ++k) {
            W1[k] = w1[m * 8 + k];
            B1[k] = b1[m * 8 + k];
            W2[k] = w2[m * 8 + k];
            sabs += fabsf(W2[k]);
        }
        const float s0 = (B2 + sabs) - 8.0f;   // wave-uniform shift; exp in fp16 range
        float gv[5];
#pragma unroll
        for (int k = 0; k < 5; ++k) {
            float h = (4 * j + k) * HSTEP;
            float s = B2 - s0;
#pragma unroll
            for (int i = 0; i < 8; ++i)
                s = fmaf(W2[i], fast_tanh(fmaf(h, W1[i], B1[i])), s);
            gv[k] = __expf(s);
        }
#pragma unroll
        for (int k = 0; k < 4; ++k)
            gt[4 * j + k] = packh2(gv[k], gv[k + 1] - gv[k]);
    }

    // ---- 4) raw barrier: wait LDS writes only, do NOT drain vmcnt ----
    asm volatile("s_waitcnt lgkmcnt(0)\n\ts_barrier" ::: "memory");

    // ---- 5) A fragments from LDS, held in registers for all 4 tiles ----
    short8 A[4][2];
#pragma unroll
    for (int wt = 0; wt < 4; ++wt)
#pragma unroll
        for (int ks = 0; ks < 2; ++ks)
            A[wt][ks] = *(const short8*)&psu[(wt * 16 + nl) * RSTRIDE + ks * 16 + q * 4];

    // ---- 6) 4-tile loop, depth-2 pipeline ----
    const int obase = (b * MM + m) * TT;
#pragma unroll
    for (int tl = 0; tl < 4; ++tl) {
        const int bank = tl & 1;

        // consume xr[bank] into Bf (this is where the vmcnt wait lands)
        short8 Bf[2][2];
        pack_tile(xr[bank], Bf);

        // prefetch tile tl+2 into the just-freed bank
        if (tl < 2)
            load_tile(xgb, (tl + 2) * 128, wv, nl, q, xr[bank]);

        // MFMA: C[w, t] = sum_v PA[v,w] * X[t,v]
        float4v C[2][4];
#pragma unroll
        for (int t2 = 0; t2 < 2; ++t2)
#pragma unroll
            for (int wt = 0; wt < 4; ++wt)
                C[t2][wt] = (float4v){0.f, 0.f, 0.f, 0.f};

#pragma unroll
        for (int t2 = 0; t2 < 2; ++t2)
#pragma unroll
            for (int wt = 0; wt < 4; ++wt) {
                C[t2][wt] = __builtin_amdgcn_mfma_f32_16x16x32_bf16(A[wt][0], Bf[t2][0], C[t2][wt], 0, 0, 0);
                C[t2][wt] = __builtin_amdgcn_mfma_f32_16x16x32_bf16(A[wt][1], Bf[t2][1], C[t2][wt], 0, 0, 0);
            }

        // epilogue: table softmax over w (rows in-thread, quads via shfl)
        const int ob = obase + tl * 128;
#pragma unroll
        for (int t2 = 0; t2 < 2; ++t2) {
            float se = 0.0f, sh = 0.0f;
#pragma unroll
            for (int wt = 0; wt < 4; ++wt) {
#pragma unroll
                for (int r = 0; r < 4; ++r) {
                    const int w = wt * 16 + q * 4 + r;
                    float h = fmaxf(fmaf(C[t2][wt][r], Amul, Cadd), 0.0f);
                    float u = fminf(h, HMAX - 0.0005f) * INVH;
                    int   i = (int)u;
                    float fr = u - (float)i;
                    unsigned p = gt[i];
                    float e = (w < VMM) ? fmaf(fr, h2f_hi(p), h2f_lo(p)) : 0.0f;
                    se += e;
                    sh = fmaf(h, e, sh);
                }
            }
            se += __shfl_xor(se, 16, 64);
            se += __shfl_xor(se, 32, 64);
            sh += __shfl_xor(sh, 16, 64);
            sh += __shfl_xor(sh, 32, 64);
            if (q == 0)
                out[ob + (wv * 2 + t2) * 16 + nl] = sh * fast_rcp(se);
        }
    }
}

extern "C" void kernel_launch(void* const* d_in, const int* in_sizes, int n_in,
                              void* d_out, int out_size, void* d_ws, size_t ws_size,
                              hipStream_t stream) {
    const float* x        = (const float*)d_in[0];
    const float* PA       = (const float*)d_in[1];
    const float* conv_w   = (const float*)d_in[2];
    const float* conv_b   = (const float*)d_in[3];
    const float* bn_gamma = (const float*)d_in[4];
    const float* bn_beta  = (const float*)d_in[5];
    const float* bn_mean  = (const float*)d_in[6];
    const float* bn_var   = (const float*)d_in[7];
    const float* w1       = (const float*)d_in[8];
    const float* b1       = (const float*)d_in[9];
    const float* w2       = (const float*)d_in[10];
    const float* b2       = (const float*)d_in[11];
    float* out = (float*)d_out;

    intra_module_agg_kernel<<<dim3(BB * MM), dim3(256), 0, stream>>>(
        x, PA, conv_w, conv_b, bn_gamma, bn_beta, bn_mean, bn_var,
        w1, b1, w2, b2, out);
}

// Round 12
// 106.147 us; speedup vs baseline: 1.0851x; 1.0377x over previous
//
#include <hip/hip_runtime.h>

// Problem constants (fixed by reference)
#define BB 64
#define TT 512
#define MM 8
#define VMM 50
#define TBLK 128         // t per block (main kernel)
#define EPSV 1e-5f

// exp(score(h)-s0) lookup table, fp16x2-packed (value, delta)
#define TN   1024
#define HMAX 16.0f
#define HSTEP (HMAX / TN)
#define INVH  (TN / HMAX)

// d_ws layout (u32 units):
//   [0, 8*TN)          : 8 per-module fp16x2 tables
//   [8*TN, +8*2048)    : 8 per-module PA^T in MFMA A-fragment order
#define WS_GT(m)   ((m) * TN)
#define WS_PAF(m)  (MM * TN + (m) * (8 * 64 * 4))
#define WS_NEED    ((MM * TN + MM * 8 * 64 * 4) * 4)   // 98304 bytes

using short8  = __attribute__((ext_vector_type(8))) short;
using float4v = __attribute__((ext_vector_type(4))) float;

__device__ __forceinline__ float fast_rcp(float x) {
    return __builtin_amdgcn_rcpf(x);
}
__device__ __forceinline__ float fast_tanh(float x) {
    float e2 = __expf(2.0f * x);
    return fmaf(-2.0f, fast_rcp(e2 + 1.0f), 1.0f);
}
__device__ __forceinline__ unsigned f2bf(float f) {
    unsigned u = __float_as_uint(f);
    return (u + 0x7FFFu + ((u >> 16) & 1u)) >> 16;
}
__device__ __forceinline__ unsigned pack2(float lo, float hi) {
    return f2bf(lo) | (f2bf(hi) << 16);
}
__device__ __forceinline__ unsigned packh2(float lo, float hi) {
    unsigned short a = __builtin_bit_cast(unsigned short, (_Float16)lo);
    unsigned short b = __builtin_bit_cast(unsigned short, (_Float16)hi);
    return (unsigned)a | ((unsigned)b << 16);
}
__device__ __forceinline__ float h2f_lo(unsigned p) {
    return (float)__builtin_bit_cast(_Float16, (unsigned short)(p & 0xFFFFu));
}
__device__ __forceinline__ float h2f_hi(unsigned p) {
    return (float)__builtin_bit_cast(_Float16, (unsigned short)(p >> 16));
}

// ---------------- prep kernel: 64 blocks = 8 modules x 8 slices ----------
// Slice parallelism cuts the serial critical path ahead of the main
// dispatch: each thread evaluates at most 2 table samples (34 transcendentals
// vs 85 in the 8-block version), PA pack split 8 ways.
__global__ __launch_bounds__(256, 4)
void prep_kernel(const float* __restrict__ PA,
                 const float* __restrict__ w1,
                 const float* __restrict__ b1,
                 const float* __restrict__ w2,
                 const float* __restrict__ b2,
                 unsigned* __restrict__ ws)
{
    const int m  = blockIdx.x >> 3;
    const int sl = blockIdx.x & 7;
    const int j  = threadIdx.x;

    if (j < 128) {
        // ---- table slice: entries [sl*128, sl*128+128) ----
        float W1[8], B1[8], W2[8];
        float B2 = b2[m], sabs = 0.0f;
#pragma unroll
        for (int k = 0; k < 8; ++k) {
            W1[k] = w1[m * 8 + k];
            B1[k] = b1[m * 8 + k];
            W2[k] = w2[m * 8 + k];
            sabs += fabsf(W2[k]);
        }
        const float s0 = (B2 + sabs) - 8.0f;   // uniform shift; exp in fp16 range
        const int  i0 = sl * 128 + j;
        float gv[2];
#pragma unroll
        for (int k = 0; k < 2; ++k) {
            float h = (i0 + k) * HSTEP;
            float s = B2 - s0;
#pragma unroll
            for (int i = 0; i < 8; ++i)
                s = fmaf(W2[i], fast_tanh(fmaf(h, W1[i], B1[i])), s);
            gv[k] = __expf(s);
        }
        ws[WS_GT(m) + i0] = packh2(gv[0], gv[1] - gv[0]);
    } else if (j < 192) {
        // ---- PA^T slice: 64 of the 512 A-fragment uint4s ----
        // Fragment A[wt][ks] for lane: w = wt*16 + (lane&15),
        // u32 cols vp = ks*16 + (lane>>4)*4 + 0..3 (bf16 v = 2vp, 2vp+1).
        const float* pa = PA + m * (VMM * VMM);
        uint4* dst = (uint4*)(ws + WS_PAF(m));
        int id   = sl * 64 + (j - 128);    // 0..511
        int wt   = id >> 7;
        int ks   = (id >> 6) & 1;
        int lane = id & 63;
        int w    = wt * 16 + (lane & 15);
        int vp0  = ks * 16 + (lane >> 4) * 4;
        unsigned u[4];
#pragma unroll
        for (int k = 0; k < 4; ++k) {
            int vp = vp0 + k, v0 = 2 * vp, v1 = v0 + 1;
            float a = (w < VMM && v0 < VMM) ? pa[v0 * VMM + w] : 0.0f;
            float c = (w < VMM && v1 < VMM) ? pa[v1 * VMM + w] : 0.0f;
            u[k] = pack2(a, c);
        }
        dst[(wt * 2 + ks) * 64 + lane] = make_uint4(u[0], u[1], u[2], u[3]);
    }
}

// ---------------- main kernel: grid = B*M*(T/128) = 2048 (r8-verified) ----
__global__ __launch_bounds__(256, 4)
void intra_module_agg_kernel(const float* __restrict__ x,
                             const float* __restrict__ conv_w,
                             const float* __restrict__ conv_b,
                             const float* __restrict__ bn_gamma,
                             const float* __restrict__ bn_beta,
                             const float* __restrict__ bn_mean,
                             const float* __restrict__ bn_var,
                             const unsigned* __restrict__ ws,
                             float* __restrict__ out)
{
    const int blk = blockIdx.x;
    const int tq  = blk & 3;          // T quarter
    const int m   = (blk >> 2) & 7;   // module
    const int b   = blk >> 5;         // batch
    const int j   = threadIdx.x;

    const int lane = j & 63, wv = j >> 6;
    const int q = lane >> 4, nl = lane & 15;

    __shared__ __align__(16) unsigned gt[TN];   // 4.1 KB only

    const float scale = bn_gamma[m] * __frsqrt_rn(bn_var[m] + EPSV);
    const float Amul  = conv_w[m] * scale;
    const float Cadd  = (conv_b[m] - bn_mean[m]) * scale + bn_beta[m];

    // ---- issue gt load (write to LDS later, overlapped with other loads) --
    uint4 g = ((const uint4*)(ws + WS_GT(m)))[j];

    // ---- A fragments: 8 coalesced dwordx4 loads, L2-hot ----
    const uint4* paf = (const uint4*)(ws + WS_PAF(m));
    uint4 Araw[4][2];
#pragma unroll
    for (int wt = 0; wt < 4; ++wt)
#pragma unroll
        for (int ks = 0; ks < 2; ++ks)
            Araw[wt][ks] = paf[(wt * 2 + ks) * 64 + lane];

    // ---- B fragments direct from x global ----
    // lane (nl,q) needs x[v = ks*32 + q*8 + jj][t]; each instr = 4 fully-used
    // 64B lines. OOB v (>=50) clamped + zeroed.
    const int t0 = tq * TBLK;
    float xr[2][16];
#pragma unroll
    for (int t2 = 0; t2 < 2; ++t2) {
        const int t = t0 + (wv * 2 + t2) * 16 + nl;
        const float* xg = x + ((b * (MM * VMM) + m * VMM) * TT + t);
#pragma unroll
        for (int jj = 0; jj < 8; ++jj) {
            xr[t2][jj] = xg[(q * 8 + jj) * TT];            // v = 0..31, valid
        }
#pragma unroll
        for (int jj = 0; jj < 8; ++jj) {
            int v  = 32 + q * 8 + jj;                      // 32..63
            int vc = (v < VMM) ? v : 0;                    // safe address
            float tv = xg[vc * TT];
            xr[t2][8 + jj] = (v < VMM) ? tv : 0.0f;
        }
    }

    // ---- gt -> LDS (overlaps with load drain of A/B) ----
    *(uint4*)&gt[4 * j] = g;

    // ---- pack B to bf16 fragments ----
    short8 Bf[2][2];
#pragma unroll
    for (int t2 = 0; t2 < 2; ++t2) {
#pragma unroll
        for (int ks = 0; ks < 2; ++ks) {
            uint4 u;
            u.x = pack2(xr[t2][8 * ks + 0], xr[t2][8 * ks + 1]);
            u.y = pack2(xr[t2][8 * ks + 2], xr[t2][8 * ks + 3]);
            u.z = pack2(xr[t2][8 * ks + 4], xr[t2][8 * ks + 5]);
            u.w = pack2(xr[t2][8 * ks + 6], xr[t2][8 * ks + 7]);
            Bf[t2][ks] = __builtin_bit_cast(short8, u);
        }
    }

    // ---- MFMA: C[w, t] = sum_v PA[v,w] * X[t,v] ----
    float4v C[2][4];
#pragma unroll
    for (int t2 = 0; t2 < 2; ++t2)
#pragma unroll
        for (int wt = 0; wt < 4; ++wt)
            C[t2][wt] = (float4v){0.f, 0.f, 0.f, 0.f};

#pragma unroll
    for (int t2 = 0; t2 < 2; ++t2) {
#pragma unroll
        for (int wt = 0; wt < 4; ++wt) {
            C[t2][wt] = __builtin_amdgcn_mfma_f32_16x16x32_bf16(
                __builtin_bit_cast(short8, Araw[wt][0]), Bf[t2][0], C[t2][wt], 0, 0, 0);
            C[t2][wt] = __builtin_amdgcn_mfma_f32_16x16x32_bf16(
                __builtin_bit_cast(short8, Araw[wt][1]), Bf[t2][1], C[t2][wt], 0, 0, 0);
        }
    }

    __syncthreads();   // gt visible to all waves

    // ---- epilogue: table softmax over w (rows in-thread, quads via shfl) --
    const int obase = (b * MM + m) * TT + t0;
#pragma unroll
    for (int t2 = 0; t2 < 2; ++t2) {
        float se = 0.0f, sh = 0.0f;
#pragma unroll
        for (int wt = 0; wt < 4; ++wt) {
#pragma unroll
            for (int r = 0; r < 4; ++r) {
                const int w = wt * 16 + q * 4 + r;
                float h = fmaxf(fmaf(C[t2][wt][r], Amul, Cadd), 0.0f);
                float u = fminf(h, HMAX - 0.0005f) * INVH;
                int   i = (int)u;
                float fr = u - (float)i;
                unsigned p = gt[i];
                float e = (w < VMM) ? fmaf(fr, h2f_hi(p), h2f_lo(p)) : 0.0f;
                se += e;
                sh = fmaf(h, e, sh);
            }
        }
        se += __shfl_xor(se, 16, 64);
        se += __shfl_xor(se, 32, 64);
        sh += __shfl_xor(sh, 16, 64);
        sh += __shfl_xor(sh, 32, 64);
        if (q == 0)
            out[obase + (wv * 2 + t2) * 16 + nl] = sh * fast_rcp(se);
    }
}

// ---------------- fallback monolithic kernel (round-6, verified) --------
#define RSTRIDE 36
__global__ __launch_bounds__(256, 4)
void mono_kernel(const float* __restrict__ x,
                 const float* __restrict__ PA,
                 const float* __restrict__ conv_w,
                 const float* __restrict__ conv_b,
                 const float* __restrict__ bn_gamma,
                 const float* __restrict__ bn_beta,
                 const float* __restrict__ bn_mean,
                 const float* __restrict__ bn_var,
                 const float* __restrict__ w1,
                 const float* __restrict__ b1,
                 const float* __restrict__ w2,
                 const float* __restrict__ b2,
                 float* __restrict__ out)
{
    const int blk = blockIdx.x;
    const int tq  = blk & 3;
    const int m   = (blk >> 2) & 7;
    const int b   = blk >> 5;
    const int j   = threadIdx.x;

    __shared__ __align__(16) unsigned xsu[TBLK * RSTRIDE];
    __shared__ __align__(16) unsigned psu[64 * RSTRIDE];
    __shared__ __align__(16) unsigned gt[TN];

    const float scale = bn_gamma[m] * __frsqrt_rn(bn_var[m] + EPSV);
    const float Amul  = conv_w[m] * scale;
    const float Cadd  = (conv_b[m] - bn_mean[m]) * scale + bn_beta[m];

    {
        const int t  = j >> 1;
        const int hf = j & 1;
        const float* xb = x + ((b * (MM * VMM) + m * VMM) * TT + tq * TBLK + t);
        unsigned* row = &xsu[t * RSTRIDE];
        const int vp0 = hf * 13;
#pragma unroll
        for (int i = 0; i < 13; ++i) {
            int vp = vp0 + i;
            float a = 0.0f, c = 0.0f;
            if (vp < 25) { a = xb[(2 * vp) * TT]; c = xb[(2 * vp + 1) * TT]; }
            row[vp] = pack2(a, c);
        }
        if (hf) {
#pragma unroll
            for (int vp = 26; vp < 32; ++vp) row[vp] = 0u;
        }
    }
    {
        const float* pa = PA + m * (VMM * VMM);
        const int w  = j & 63;
        const int vb = (j >> 6) * 8;
#pragma unroll
        for (int i = 0; i < 8; ++i) {
            int vp = vb + i, v0 = 2 * vp, v1 = v0 + 1;
            float a = (w < VMM && v0 < VMM) ? pa[v0 * VMM + w] : 0.0f;
            float c = (w < VMM && v1 < VMM) ? pa[v1 * VMM + w] : 0.0f;
            psu[w * RSTRIDE + vp] = pack2(a, c);
        }
    }
    {
        float W1[8], B1[8], W2[8];
        float B2 = b2[m], sabs = 0.0f;
#pragma unroll
        for (int k = 0; k < 8; ++k) {
            W1[k] = w1[m * 8 + k];
            B1[k] = b1[m * 8 + k];
            W2[k] = w2[m * 8 + k];
            sabs += fabsf(W2[k]);
        }
        const float s0 = (B2 + sabs) - 8.0f;
        float gv[5];
#pragma unroll
        for (int k = 0; k < 5; ++k) {
            float h = (4 * j + k) * HSTEP;
            float s = B2 - s0;
#pragma unroll
            for (int i = 0; i < 8; ++i)
                s = fmaf(W2[i], fast_tanh(fmaf(h, W1[i], B1[i])), s);
            gv[k] = __expf(s);
        }
#pragma unroll
        for (int k = 0; k < 4; ++k)
            gt[4 * j + k] = packh2(gv[k], gv[k + 1] - gv[k]);
    }

    __syncthreads();

    const int lane = j & 63, wv = j >> 6;
    const int q = lane >> 4, nl = lane & 15;

    short8 A[4][2];
#pragma unroll
    for (int wt = 0; wt < 4; ++wt)
#pragma unroll
        for (int ks = 0; ks < 2; ++ks)
            A[wt][ks] = *(const short8*)&psu[(wt * 16 + nl) * RSTRIDE + ks * 16 + q * 4];

    float4v C[2][4];
#pragma unroll
    for (int t2 = 0; t2 < 2; ++t2)
#pragma unroll
        for (int wt = 0; wt < 4; ++wt)
            C[t2][wt] = (float4v){0.f, 0.f, 0.f, 0.f};

#pragma unroll
    for (int t2 = 0; t2 < 2; ++t2) {
        const int trow = (wv * 2 + t2) * 16 + nl;
        short8 Bv0 = *(const short8*)&xsu[trow * RSTRIDE + 0 * 16 + q * 4];
        short8 Bv1 = *(const short8*)&xsu[trow * RSTRIDE + 1 * 16 + q * 4];
#pragma unroll
        for (int wt = 0; wt < 4; ++wt) {
            C[t2][wt] = __builtin_amdgcn_mfma_f32_16x16x32_bf16(A[wt][0], Bv0, C[t2][wt], 0, 0, 0);
            C[t2][wt] = __builtin_amdgcn_mfma_f32_16x16x32_bf16(A[wt][1], Bv1, C[t2][wt], 0, 0, 0);
        }
    }

    const int obase = (b * MM + m) * TT + tq * TBLK;
#pragma unroll
    for (int t2 = 0; t2 < 2; ++t2) {
        float se = 0.0f, sh = 0.0f;
#pragma unroll
        for (int wt = 0; wt < 4; ++wt) {
#pragma unroll
            for (int r = 0; r < 4; ++r) {
                const int w = wt * 16 + q * 4 + r;
                float h = fmaxf(fmaf(C[t2][wt][r], Amul, Cadd), 0.0f);
                float u = fminf(h, HMAX - 0.0005f) * INVH;
                int   i = (int)u;
                float fr = u - (float)i;
                unsigned p = gt[i];
                float e = (w < VMM) ? fmaf(fr, h2f_hi(p), h2f_lo(p)) : 0.0f;
                se += e;
                sh = fmaf(h, e, sh);
            }
        }
        se += __shfl_xor(se, 16, 64);
        se += __shfl_xor(se, 32, 64);
        sh += __shfl_xor(sh, 16, 64);
        sh += __shfl_xor(sh, 32, 64);
        if (q == 0)
            out[obase + (wv * 2 + t2) * 16 + nl] = sh * fast_rcp(se);
    }
}

extern "C" void kernel_launch(void* const* d_in, const int* in_sizes, int n_in,
                              void* d_out, int out_size, void* d_ws, size_t ws_size,
                              hipStream_t stream) {
    const float* x        = (const float*)d_in[0];
    const float* PA       = (const float*)d_in[1];
    const float* conv_w   = (const float*)d_in[2];
    const float* conv_b   = (const float*)d_in[3];
    const float* bn_gamma = (const float*)d_in[4];
    const float* bn_beta  = (const float*)d_in[5];
    const float* bn_mean  = (const float*)d_in[6];
    const float* bn_var   = (const float*)d_in[7];
    const float* w1       = (const float*)d_in[8];
    const float* b1       = (const float*)d_in[9];
    const float* w2       = (const float*)d_in[10];
    const float* b2       = (const float*)d_in[11];
    float* out = (float*)d_out;

    if (ws_size >= (size_t)WS_NEED) {
        unsigned* ws = (unsigned*)d_ws;
        prep_kernel<<<dim3(MM * 8), dim3(256), 0, stream>>>(PA, w1, b1, w2, b2, ws);
        intra_module_agg_kernel<<<dim3(BB * MM * (TT / TBLK)), dim3(256), 0, stream>>>(
            x, conv_w, conv_b, bn_gamma, bn_beta, bn_mean, bn_var, ws, out);
    } else {
        mono_kernel<<<dim3(BB * MM * (TT / TBLK)), dim3(256), 0, stream>>>(
            x, PA, conv_w, conv_b, bn_gamma, bn_beta, bn_mean, bn_var,
            w1, b1, w2, b2, out);
    }
}